// Round 8
// baseline (2167.830 us; speedup 1.0000x reference)
//
#include <hip/hip_runtime.h>
#include <math.h>

// leaky_current_RNN: B=128, T=512, I=4, H=512, O=3, alpha=0.5, n_reg=256.
// R8: same-XCD L2 exchange with SELF-VALIDATING (value|tag) u64 words.
//  - R7 postmortem: separate data+tag stores relied on vmcnt(0) implying
//    L2-visibility ordering -> stale data under a valid tag. Fix: fast path
//    uses the R3/R5-proven single-u64 (value,tag) word -- seen whole-old or
//    whole-new, no ordering dependence. Producer plain-stores (write-through
//    to XCD L2); consumer polls its own words with sc0 loads (L1 bypass).
//  - Dual publish (fast word + agent word) + sticky 2048-poll timeout
//    fallback to the agent path: hang-impossible, worst case = R5 perf.
//  - fdat rows are 4KB group-exclusive: no line is written from two XCDs.

#define BB 128
#define TT 512
#define II 4
#define HH 512
#define OO 3
#define NREG_ 256

#define NTHREADS 512
#define MEMBERS 4
#define ROWS 2
#define NGROUPS 64
#define NBLOCKS (NGROUPS * MEMBERS)

// d_ws layout (bytes)
#define WS_ADAT  16384                          // u64 adat[2][64][2][512] = 1MB
#define WS_FDAT  (WS_ADAT + 1048576)            // u64 fdat[2][64][2][512] = 1MB
#define WS_PART  (WS_FDAT + 1048576)            // f32 partials[256]
#define WS_ZERO  WS_PART                        // memset: ctrl+adat+fdat

typedef unsigned long long u64;
typedef unsigned int u32;
typedef __attribute__((ext_vector_type(2))) float f32x2;

__device__ __forceinline__ u64 aload(const u64* p) {
    return __hip_atomic_load(p, __ATOMIC_RELAXED, __HIP_MEMORY_SCOPE_AGENT);
}
__device__ __forceinline__ void astore(u64* p, u64 v) {
    __hip_atomic_store(p, v, __ATOMIC_RELAXED, __HIP_MEMORY_SCOPE_AGENT);
}
__device__ __forceinline__ float fast_tanh(float x) {
    float ax = fabsf(x);
    float e  = __expf(2.0f * ax);
    float r  = 1.0f - 2.0f * __builtin_amdgcn_rcpf(e + 1.0f);
    return copysignf(r, x);
}

#define R16(M) M(0) M(1) M(2) M(3) M(4) M(5) M(6) M(7) \
               M(8) M(9) M(10) M(11) M(12) M(13) M(14) M(15)

#define WLD(Q) \
    f32x2 w##Q##a, w##Q##b, w##Q##c, w##Q##d; \
    w##Q##a.x = Wp[(size_t)(4*Q+0)*HH]; w##Q##a.y = Wp[(size_t)(4*Q+0)*HH+64]; \
    w##Q##b.x = Wp[(size_t)(4*Q+1)*HH]; w##Q##b.y = Wp[(size_t)(4*Q+1)*HH+64]; \
    w##Q##c.x = Wp[(size_t)(4*Q+2)*HH]; w##Q##c.y = Wp[(size_t)(4*Q+2)*HH+64]; \
    w##Q##d.x = Wp[(size_t)(4*Q+3)*HH]; w##Q##d.y = Wp[(size_t)(4*Q+3)*HH+64];

#define KSTEP(K, W) { \
    u32 a0_ = __builtin_amdgcn_readlane(__float_as_uint(ar0), (K)); \
    u32 a1_ = __builtin_amdgcn_readlane(__float_as_uint(ar1), (K)); \
    u64 ab_ = (u64)a0_ | ((u64)a1_ << 32); \
    asm("v_pk_fma_f32 %0, %2, %3, %0 op_sel_hi:[1,0,1]\n\t" \
        "v_pk_fma_f32 %1, %2, %3, %1 op_sel:[0,1,0] op_sel_hi:[1,1,1]" \
        : "+v"(accA), "+v"(accB) : "s"(ab_), "v"(W)); }

#define MV(Q) KSTEP(4*Q+0, w##Q##a) KSTEP(4*Q+1, w##Q##b) \
              KSTEP(4*Q+2, w##Q##c) KSTEP(4*Q+3, w##Q##d)

__global__ __launch_bounds__(NTHREADS) __attribute__((amdgpu_waves_per_eu(2, 2)))
void rnn_main(const float* __restrict__ x,
              const float* __restrict__ h0,
              const float* __restrict__ W_rec,
              const float* __restrict__ W_in,
              const float* __restrict__ bias_rec,
              const float* __restrict__ bias_in,
              float* __restrict__ hidden,
              u32* __restrict__ ws_u32,
              float* __restrict__ partials)
{
    const int tid  = threadIdx.x;
    const int wid  = tid >> 6;
    const int lane = tid & 63;

    u64* adat = (u64*)((char*)ws_u32 + WS_ADAT);
    u64* fdat = (u64*)((char*)ws_u32 + WS_FDAT);

    __shared__ int sh_g, sh_mm, sh_fast;
    __shared__ float sc_s[2][ROWS][128][9];
    __shared__ float xbuf[ROWS * TT * II];
    __shared__ float win_s[II][128];
    __shared__ float ub_s[128];
    __shared__ float red_s[NTHREADS / 64];

    // ---- dynamic same-XCD grouping (perf-only; fallback covers misgrouping) --
    if (tid == 0) {
        u32 xcc;
        asm volatile("s_getreg_b32 %0, hwreg(HW_REG_XCC_ID)" : "=s"(xcc));
        int xcd = (int)(xcc & 7u);
        u32* totalp = ws_u32;
        u32* cnt    = ws_u32 + 1;
        int rank = (int)atomicAdd(&cnt[xcd], 1u);
        __hip_atomic_fetch_add(totalp, 1u, __ATOMIC_RELEASE, __HIP_MEMORY_SCOPE_AGENT);
        while (__hip_atomic_load(totalp, __ATOMIC_ACQUIRE, __HIP_MEMORY_SCOPE_AGENT)
               < (u32)NBLOCKS)
            __builtin_amdgcn_s_sleep(2);
        u32 c[8];
        for (int i = 0; i < 8; ++i)
            c[i] = __hip_atomic_load(&cnt[i], __ATOMIC_RELAXED, __HIP_MEMORY_SCOPE_AGENT);
        int gb = 0, g = -1, mm = 0, fast = 0;
        for (int xx = 0; xx < 8; ++xx) {
            int ng = (int)(c[xx] >> 2);
            if (xx == xcd && rank < 4 * ng) {
                g = gb + (rank >> 2); mm = rank & 3; fast = 1;
            }
            gb += ng;
        }
        if (g < 0) {
            int lidx = 0;
            for (int xx = 0; xx < xcd; ++xx) lidx += (int)(c[xx] & 3u);
            lidx += rank - 4 * (int)(c[xcd] >> 2);
            g = gb + (lidx >> 2); mm = lidx & 3; fast = 0;
        }
        sh_g = g; sh_mm = mm; sh_fast = fast;
    }
    __syncthreads();
    const int g    = sh_g;
    const int memb = sh_mm;
    const int fast = sh_fast;
    const int r0   = g * ROWS;

    // ---- one-time staging ----
    for (int idx = tid; idx < ROWS * TT * II; idx += NTHREADS) {
        int r = idx >> 11, rem = idx & (TT * II - 1);
        xbuf[idx] = x[(size_t)(r0 + r) * (TT * II) + rem];
    }
    if (tid < II * 128) {
        int i = tid >> 7, jj = tid & 127;
        win_s[i][jj] = W_in[i * HH + memb * 128 + jj];
    }
    if (tid < 128) {
        ub_s[tid] = bias_rec[memb * 128 + tid] + bias_in[memb * 128 + tid];
    }

    // ---- W_rec slice into registers as float2 (colA,colB) pairs ----
    const float* Wp = W_rec + (size_t)(wid * 64) * HH + memb * 128 + lane;
    R16(WLD)

    // ---- prologue publish: a_0 with tag 1 (dual in fast groups) ----
    const int fr  = tid >> 7;
    const int fj  = tid & 127;
    const int fjg = memb * 128 + fj;
    float hprev = 0.0f, zprev = 0.0f, racc = 0.0f;
    if (tid < ROWS * 128) {
        hprev = h0[(size_t)(r0 + fr) * HH + fjg];
        float a0v = fast_tanh(hprev);
        u64 pv = (u64)__float_as_uint(a0v) | ((u64)1u << 32);
        size_t pidx = ((size_t)(0 * NGROUPS + g) * 2 + fr) * HH + fjg;
        if (fast) fdat[pidx] = pv;        // plain: write-through to XCD L2
        astore(&adat[pidx], pv);          // agent: always valid
        hidden[(size_t)(r0 + fr) * HH + fjg] = hprev;
    }

    int fastmode = fast;   // sticky per-wave consumption mode

#pragma unroll 1
    for (int t = 0; t < TT; ++t) {
        const int slot = t & 1;
        const u32 tagc = (u32)(t + 1);

        // ---- acquire own activation window (self-validating words) ----
        float ar0, ar1;
        {
            u64 u0 = 0, u1 = 0;
            bool got = false;
            const size_t base = ((size_t)(slot * NGROUPS + g) * 2) * HH
                                + wid * 64 + lane;
            if (fastmode) {
                const u64* f0 = fdat + base;
                const u64* f1 = f0 + HH;
                int it = 0;
                for (;;) {
                    asm volatile("global_load_dwordx2 %0, %2, off sc0\n\t"
                                 "global_load_dwordx2 %1, %3, off sc0\n\t"
                                 "s_waitcnt vmcnt(0)"
                                 : "=v"(u0), "=v"(u1)
                                 : "v"(f0), "v"(f1) : "memory");
                    bool ok = ((u32)(u0 >> 32) == tagc) & ((u32)(u1 >> 32) == tagc);
                    if (__all(ok)) { got = true; break; }
                    if (++it > 2048) { fastmode = 0; break; }
                }
            }
            if (!got) {
                const u64* p0 = adat + base;
                const u64* p1 = p0 + HH;
                for (;;) {
                    u0 = aload(p0);
                    u1 = aload(p1);
                    bool ok = ((u32)(u0 >> 32) == tagc) & ((u32)(u1 >> 32) == tagc);
                    if (__all(ok)) break;
                }
            }
            ar0 = __uint_as_float((u32)u0);
            ar1 = __uint_as_float((u32)u1);
        }

        // ---- matvec: pk_fma with packed-row accumulators (R5-exact) ----
        f32x2 accA = {0.0f, 0.0f};
        f32x2 accB = {0.0f, 0.0f};
        R16(MV)

        sc_s[slot][0][lane][wid]      = accA.x;
        sc_s[slot][1][lane][wid]      = accA.y;
        sc_s[slot][0][lane + 64][wid] = accB.x;
        sc_s[slot][1][lane + 64][wid] = accB.y;
        __syncthreads();

        // ---- finalize (waves 0-3): reduce, z, h_new, publish ----
        if (tid < ROWS * 128) {
            float q0 = sc_s[slot][fr][fj][0], q1 = sc_s[slot][fr][fj][1];
            float q2 = sc_s[slot][fr][fj][2], q3 = sc_s[slot][fr][fj][3];
            float q4 = sc_s[slot][fr][fj][4], q5 = sc_s[slot][fr][fj][5];
            float q6 = sc_s[slot][fr][fj][6], q7 = sc_s[slot][fr][fj][7];
            float z = ((q0 + q1) + (q2 + q3)) + ((q4 + q5) + (q6 + q7));
            z += ub_s[fj];
            const float* xr = &xbuf[fr * (TT * II) + t * II];
            z = fmaf(xr[0], win_s[0][fj], z);
            z = fmaf(xr[1], win_s[1][fj], z);
            z = fmaf(xr[2], win_s[2][fj], z);
            z = fmaf(xr[3], win_s[3][fj], z);
            float hn = 0.5f * hprev + 0.5f * z;
            float av = fast_tanh(hn);
            const int slot2 = (t + 1) & 1;
            u64 pv = (u64)__float_as_uint(av) | ((u64)(tagc + 1) << 32);
            size_t pidx = ((size_t)(slot2 * NGROUPS + g) * 2 + fr) * HH + fjg;
            if (fast) fdat[pidx] = pv;
            astore(&adat[pidx], pv);
            hidden[(size_t)(t + 1) * BB * HH + (size_t)(r0 + fr) * HH + fjg] = hn;
            if (fjg < NREG_) {
                float d1 = hn - hprev;
                racc = fmaf(d1, d1, racc);
                if (t > 0) { float d2 = z - zprev; racc = fmaf(d2, d2, racc); }
                zprev = z;
            }
            hprev = hn;
        }
        // no tail barrier: sc_s double-buffered; publishes gate overwrite
    }

    // ---- block-reduce reg partial (stored by ROLE for determinism) ----
    for (int off = 32; off; off >>= 1) racc += __shfl_down(racc, off);
    if ((tid & 63) == 0) red_s[tid >> 6] = racc;
    __syncthreads();
    if (tid == 0) {
        float s = 0.0f;
        for (int i = 0; i < NTHREADS / 64; ++i) s += red_s[i];
        partials[g * MEMBERS + memb] = s;
    }
}

// outputs[b][t][:] = hidden[t+1][b][:] @ W_out   (one wave per (b,t))
__global__ __launch_bounds__(256)
void rnn_out(const float* __restrict__ hidden,
             const float* __restrict__ W_out,
             float* __restrict__ outputs)
{
    __shared__ float wout_s[HH * OO];
    const int tid = threadIdx.x;
    for (int i = tid; i < HH * OO; i += 256) wout_s[i] = W_out[i];
    __syncthreads();

    const int gid  = blockIdx.x * 4 + (tid >> 6);
    const int lane = tid & 63;
    const int b = gid >> 9;
    const int t = gid & (TT - 1);
    const float* hp = hidden + (size_t)(t + 1) * BB * HH + (size_t)b * HH;

    float o0 = 0.0f, o1 = 0.0f, o2 = 0.0f;
#pragma unroll
    for (int q = 0; q < 8; ++q) {
        int k = lane + 64 * q;
        float hv = hp[k];
        o0 = fmaf(hv, wout_s[k * 3 + 0], o0);
        o1 = fmaf(hv, wout_s[k * 3 + 1], o1);
        o2 = fmaf(hv, wout_s[k * 3 + 2], o2);
    }
    for (int off = 32; off; off >>= 1) {
        o0 += __shfl_down(o0, off);
        o1 += __shfl_down(o1, off);
        o2 += __shfl_down(o2, off);
    }
    if (lane == 0) {
        float* op = outputs + (size_t)(b * TT + t) * OO;
        op[0] = o0; op[1] = o1; op[2] = o2;
    }
}

__global__ __launch_bounds__(256)
void rnn_tcr(const float* __restrict__ partials, float* __restrict__ tcr)
{
    __shared__ float red[4];
    const int tid = threadIdx.x;
    float v = partials[tid];
    for (int off = 32; off; off >>= 1) v += __shfl_down(v, off);
    if ((tid & 63) == 0) red[tid >> 6] = v;
    __syncthreads();
    if (tid == 0) {
        float s = red[0] + red[1] + red[2] + red[3];
        *tcr = s * (1.0f / ((float)TT * (float)BB * (float)NREG_));
    }
}

extern "C" void kernel_launch(void* const* d_in, const int* in_sizes, int n_in,
                              void* d_out, int out_size, void* d_ws, size_t ws_size,
                              hipStream_t stream)
{
    (void)in_sizes; (void)n_in; (void)out_size; (void)ws_size;

    const float* x     = (const float*)d_in[0];
    const float* h0    = (const float*)d_in[1];
    const float* W_rec = (const float*)d_in[2];
    const float* W_in  = (const float*)d_in[3];
    const float* W_out = (const float*)d_in[4];
    const float* brec  = (const float*)d_in[5];
    const float* bin   = (const float*)d_in[6];

    float* out     = (float*)d_out;
    float* outputs = out;
    float* hidden  = out + (size_t)BB * TT * OO;
    float* tcr     = out + (size_t)BB * TT * OO + (size_t)(TT + 1) * BB * HH;

    u32*   ws_u32   = (u32*)d_ws;
    float* partials = (float*)((char*)d_ws + WS_PART);

    // zero ctrl + adat + fdat every call (graph replays reuse d_ws)
    (void)hipMemsetAsync(d_ws, 0, WS_ZERO, stream);

    void* args[] = { (void*)&x, (void*)&h0, (void*)&W_rec, (void*)&W_in,
                     (void*)&brec, (void*)&bin, (void*)&hidden,
                     (void*)&ws_u32, (void*)&partials };
    (void)hipLaunchCooperativeKernel((const void*)rnn_main,
                                     dim3(NBLOCKS), dim3(NTHREADS),
                                     args, 0, stream);

    rnn_out<<<dim3((BB * TT) / 4), dim3(256), 0, stream>>>(hidden, W_out, outputs);
    rnn_tcr<<<dim3(1), dim3(256), 0, stream>>>(partials, tcr);
}

// Round 9
// 1205.838 us; speedup vs baseline: 1.7978x; 1.7978x over previous
//
#include <hip/hip_runtime.h>
#include <math.h>

// leaky_current_RNN: B=128, T=512, I=4, H=512, O=3, alpha=0.5, n_reg=256.
// R9: consolidation on the proven R5 structure (agent-scope self-validating
// (value|tag) u64 exchange, single barrier/step, static grouping).
//  - R8 postmortem: same-XCD plain-store/sc0 exchange unreliable (3 strikes:
//    deadlock/stale/slow) -- removed entirely.
//  - Matvec: plain-C fmaf with wave-uniform readlane broadcast (SGPR src),
//    no inline asm "v" constraints -> no forced AGPR->VGPR copies per FMA.
//  - Producers publish RAW h (tanh moved to consumers, data-parallel).

#define BB 128
#define TT 512
#define II 4
#define HH 512
#define OO 3
#define NREG_ 256

#define NTHREADS 512
#define MEMBERS 4
#define ROWS 2
#define NGROUPS 64
#define NBLOCKS (NGROUPS * MEMBERS)

// d_ws layout (bytes)
#define WS_ADAT  0                              // u64 adat[2][64][2][512] = 1MB
#define WS_PART  (2 * NGROUPS * 2 * HH * 8)     // f32 partials[256]

typedef unsigned long long u64;
typedef unsigned int u32;
typedef __attribute__((ext_vector_type(2))) float f32x2;

__device__ __forceinline__ u64 aload(const u64* p) {
    return __hip_atomic_load(p, __ATOMIC_RELAXED, __HIP_MEMORY_SCOPE_AGENT);
}
__device__ __forceinline__ void astore(u64* p, u64 v) {
    __hip_atomic_store(p, v, __ATOMIC_RELAXED, __HIP_MEMORY_SCOPE_AGENT);
}
__device__ __forceinline__ float rlane(float v, int l) {
    return __uint_as_float(__builtin_amdgcn_readlane(__float_as_uint(v), l));
}
__device__ __forceinline__ float fast_tanh(float x) {
    float ax = fabsf(x);
    float e  = __expf(2.0f * ax);
    float r  = 1.0f - 2.0f * __builtin_amdgcn_rcpf(e + 1.0f);
    return copysignf(r, x);
}

#define R16(M) M(0) M(1) M(2) M(3) M(4) M(5) M(6) M(7) \
               M(8) M(9) M(10) M(11) M(12) M(13) M(14) M(15)

// Weight pairs: w.x = W[k][memb*128+lane], w.y = W[k][memb*128+64+lane]
#define WLD(Q) \
    f32x2 w##Q##a, w##Q##b, w##Q##c, w##Q##d; \
    w##Q##a.x = Wp[(size_t)(4*Q+0)*HH]; w##Q##a.y = Wp[(size_t)(4*Q+0)*HH+64]; \
    w##Q##b.x = Wp[(size_t)(4*Q+1)*HH]; w##Q##b.y = Wp[(size_t)(4*Q+1)*HH+64]; \
    w##Q##c.x = Wp[(size_t)(4*Q+2)*HH]; w##Q##c.y = Wp[(size_t)(4*Q+2)*HH+64]; \
    w##Q##d.x = Wp[(size_t)(4*Q+3)*HH]; w##Q##d.y = Wp[(size_t)(4*Q+3)*HH+64];

// Plain-C: s0/s1 are wave-uniform (SGPR); v_fmac_f32 dst, s, v_w.
#define KSTEP(K, W) { \
    float s0 = rlane(ar0, (K)); \
    float s1 = rlane(ar1, (K)); \
    accA.x = fmaf(s0, W.x, accA.x); \
    accA.y = fmaf(s1, W.x, accA.y); \
    accB.x = fmaf(s0, W.y, accB.x); \
    accB.y = fmaf(s1, W.y, accB.y); }

#define MV(Q) KSTEP(4*Q+0, w##Q##a) KSTEP(4*Q+1, w##Q##b) \
              KSTEP(4*Q+2, w##Q##c) KSTEP(4*Q+3, w##Q##d)

// adat layout: [slot][group][row][col] of u64 (h_value, tag)
__global__ __launch_bounds__(NTHREADS) __attribute__((amdgpu_waves_per_eu(2, 2)))
void rnn_main(const float* __restrict__ x,
              const float* __restrict__ h0,
              const float* __restrict__ W_rec,
              const float* __restrict__ W_in,
              const float* __restrict__ bias_rec,
              const float* __restrict__ bias_in,
              float* __restrict__ hidden,      // (T+1, B, H) region of d_out
              u64* __restrict__ adat,          // exchange buffer in d_ws
              float* __restrict__ partials)
{
    const int tid  = threadIdx.x;
    const int bid  = blockIdx.x;
    const int xcd  = bid & 7;
    const int onx  = bid >> 3;
    const int memb = onx & (MEMBERS - 1);
    const int g    = xcd * 8 + (onx >> 2);    // 0..63
    const int r0   = g * ROWS;
    const int wid  = tid >> 6;                // k-window [64*wid, 64*wid+64)
    const int lane = tid & 63;

    __shared__ float sc_s[2][ROWS][128][9];   // double-buffered split-k partials
    __shared__ float xbuf[ROWS * TT * II];
    __shared__ float win_s[II][128];
    __shared__ float ub_s[128];
    __shared__ float red_s[NTHREADS / 64];

    // ---- one-time staging ----
    for (int idx = tid; idx < ROWS * TT * II; idx += NTHREADS) {
        int r = idx >> 11, rem = idx & (TT * II - 1);
        xbuf[idx] = x[(size_t)(r0 + r) * (TT * II) + rem];
    }
    if (tid < II * 128) {
        int i = tid >> 7, jj = tid & 127;
        win_s[i][jj] = W_in[i * HH + memb * 128 + jj];
    }
    if (tid < 128) {
        ub_s[tid] = bias_rec[memb * 128 + tid] + bias_in[memb * 128 + tid];
    }

    // ---- W_rec slice into registers as float2 (colA,colB) pairs ----
    const float* Wp = W_rec + (size_t)(wid * 64) * HH + memb * 128 + lane;
    R16(WLD)

    // ---- prologue publish: raw h0 with tag 1 ----
    const int fr  = tid >> 7;           // valid when tid < 256
    const int fj  = tid & 127;
    const int fjg = memb * 128 + fj;
    float hprev = 0.0f, zprev = 0.0f, racc = 0.0f;
    if (tid < ROWS * 128) {
        hprev = h0[(size_t)(r0 + fr) * HH + fjg];
        u64 pv = (u64)__float_as_uint(hprev) | ((u64)1u << 32);
        astore(&adat[((size_t)(0 * NGROUPS + g) * 2 + fr) * HH + fjg], pv);
        hidden[(size_t)(r0 + fr) * HH + fjg] = hprev;   // hidden[0] = h0
    }

#pragma unroll 1
    for (int t = 0; t < TT; ++t) {
        const int slot = t & 1;
        const u32 tagc = (u32)(t + 1);

        // ---- poll own h window (self-validating (value|tag) words) ----
        const u64* p0 = adat + ((size_t)(slot * NGROUPS + g) * 2) * HH
                        + wid * 64 + lane;
        const u64* p1 = p0 + HH;
        u64 u0, u1;
        for (;;) {
            u0 = aload(p0);
            u1 = aload(p1);
            bool ok = ((u32)(u0 >> 32) == tagc) & ((u32)(u1 >> 32) == tagc);
            if (__all(ok)) break;
        }
        // consumer-side tanh (data-parallel, off the producer critical path)
        float ar0 = fast_tanh(__uint_as_float((u32)u0));
        float ar1 = fast_tanh(__uint_as_float((u32)u1));

        // ---- matvec: uniform-broadcast FMAs against register weights ----
        f32x2 accA = {0.0f, 0.0f};   // (row0, row1) x colA = lane
        f32x2 accB = {0.0f, 0.0f};   // (row0, row1) x colB = lane+64
        R16(MV)

        sc_s[slot][0][lane][wid]      = accA.x;
        sc_s[slot][1][lane][wid]      = accA.y;
        sc_s[slot][0][lane + 64][wid] = accB.x;
        sc_s[slot][1][lane + 64][wid] = accB.y;
        __syncthreads();   // single barrier per step (sc_s double-buffered)

        // ---- finalize (waves 0-3): reduce, z, h_new, publish ----
        if (tid < ROWS * 128) {
            float q0 = sc_s[slot][fr][fj][0], q1 = sc_s[slot][fr][fj][1];
            float q2 = sc_s[slot][fr][fj][2], q3 = sc_s[slot][fr][fj][3];
            float q4 = sc_s[slot][fr][fj][4], q5 = sc_s[slot][fr][fj][5];
            float q6 = sc_s[slot][fr][fj][6], q7 = sc_s[slot][fr][fj][7];
            float z = ((q0 + q1) + (q2 + q3)) + ((q4 + q5) + (q6 + q7));
            z += ub_s[fj];
            const float* xr = &xbuf[fr * (TT * II) + t * II];
            z = fmaf(xr[0], win_s[0][fj], z);
            z = fmaf(xr[1], win_s[1][fj], z);
            z = fmaf(xr[2], win_s[2][fj], z);
            z = fmaf(xr[3], win_s[3][fj], z);
            float hn = 0.5f * hprev + 0.5f * z;
            const int slot2 = (t + 1) & 1;
            u64 pv = (u64)__float_as_uint(hn) | ((u64)(tagc + 1) << 32);
            astore(&adat[((size_t)(slot2 * NGROUPS + g) * 2 + fr) * HH + fjg], pv);
            hidden[(size_t)(t + 1) * BB * HH + (size_t)(r0 + fr) * HH + fjg] = hn;
            if (fjg < NREG_) {
                float d1 = hn - hprev;
                racc = fmaf(d1, d1, racc);
                if (t > 0) { float d2 = z - zprev; racc = fmaf(d2, d2, racc); }
                zprev = z;
            }
            hprev = hn;
        }
        // no tail barrier: sc_s double-buffered; publishes gate overwrite
    }

    // ---- block-reduce reg partial (stored by ROLE for determinism) ----
    for (int off = 32; off; off >>= 1) racc += __shfl_down(racc, off);
    if ((tid & 63) == 0) red_s[tid >> 6] = racc;
    __syncthreads();
    if (tid == 0) {
        float s = 0.0f;
        for (int i = 0; i < NTHREADS / 64; ++i) s += red_s[i];
        partials[g * MEMBERS + memb] = s;
    }
}

// outputs[b][t][:] = hidden[t+1][b][:] @ W_out   (one wave per (b,t))
__global__ __launch_bounds__(256)
void rnn_out(const float* __restrict__ hidden,
             const float* __restrict__ W_out,
             float* __restrict__ outputs)
{
    __shared__ float wout_s[HH * OO];
    const int tid = threadIdx.x;
    for (int i = tid; i < HH * OO; i += 256) wout_s[i] = W_out[i];
    __syncthreads();

    const int gid  = blockIdx.x * 4 + (tid >> 6);
    const int lane = tid & 63;
    const int b = gid >> 9;
    const int t = gid & (TT - 1);
    const float* hp = hidden + (size_t)(t + 1) * BB * HH + (size_t)b * HH;

    float o0 = 0.0f, o1 = 0.0f, o2 = 0.0f;
#pragma unroll
    for (int q = 0; q < 8; ++q) {
        int k = lane + 64 * q;
        float hv = hp[k];
        o0 = fmaf(hv, wout_s[k * 3 + 0], o0);
        o1 = fmaf(hv, wout_s[k * 3 + 1], o1);
        o2 = fmaf(hv, wout_s[k * 3 + 2], o2);
    }
    for (int off = 32; off; off >>= 1) {
        o0 += __shfl_down(o0, off);
        o1 += __shfl_down(o1, off);
        o2 += __shfl_down(o2, off);
    }
    if (lane == 0) {
        float* op = outputs + (size_t)(b * TT + t) * OO;
        op[0] = o0; op[1] = o1; op[2] = o2;
    }
}

__global__ __launch_bounds__(256)
void rnn_tcr(const float* __restrict__ partials, float* __restrict__ tcr)
{
    __shared__ float red[4];
    const int tid = threadIdx.x;
    float v = partials[tid];
    for (int off = 32; off; off >>= 1) v += __shfl_down(v, off);
    if ((tid & 63) == 0) red[tid >> 6] = v;
    __syncthreads();
    if (tid == 0) {
        float s = red[0] + red[1] + red[2] + red[3];
        *tcr = s * (1.0f / ((float)TT * (float)BB * (float)NREG_));
    }
}

extern "C" void kernel_launch(void* const* d_in, const int* in_sizes, int n_in,
                              void* d_out, int out_size, void* d_ws, size_t ws_size,
                              hipStream_t stream)
{
    (void)in_sizes; (void)n_in; (void)out_size; (void)ws_size;

    const float* x     = (const float*)d_in[0];
    const float* h0    = (const float*)d_in[1];
    const float* W_rec = (const float*)d_in[2];
    const float* W_in  = (const float*)d_in[3];
    const float* W_out = (const float*)d_in[4];
    const float* brec  = (const float*)d_in[5];
    const float* bin   = (const float*)d_in[6];

    float* out     = (float*)d_out;
    float* outputs = out;
    float* hidden  = out + (size_t)BB * TT * OO;
    float* tcr     = out + (size_t)BB * TT * OO + (size_t)(TT + 1) * BB * HH;

    u64*   adat     = (u64*)((char*)d_ws + WS_ADAT);
    float* partials = (float*)((char*)d_ws + WS_PART);

    // zero exchange-buffer tags every call (graph replays reuse d_ws)
    (void)hipMemsetAsync(d_ws, 0, WS_PART, stream);

    void* args[] = { (void*)&x, (void*)&h0, (void*)&W_rec, (void*)&W_in,
                     (void*)&brec, (void*)&bin, (void*)&hidden,
                     (void*)&adat, (void*)&partials };
    (void)hipLaunchCooperativeKernel((const void*)rnn_main,
                                     dim3(NBLOCKS), dim3(NTHREADS),
                                     args, 0, stream);

    rnn_out<<<dim3((BB * TT) / 4), dim3(256), 0, stream>>>(hidden, W_out, outputs);
    rnn_tcr<<<dim3(1), dim3(256), 0, stream>>>(partials, tcr);
}

// Round 10
// 987.078 us; speedup vs baseline: 2.1962x; 1.2216x over previous
//
#include <hip/hip_runtime.h>
#include <math.h>

// leaky_current_RNN: B=128, T=512, I=4, H=512, O=3, alpha=0.5, n_reg=256.
// R10: two-cohort pipelining. Weights are row-independent, so each block
// serves TWO rows (cohort A = row g, cohort B = row 64+g) in alternating
// phases; the LLC publish->poll latency of cohort A overlaps with cohort B's
// matvec+finalize (and vice versa). Exchange protocol, pk_fma encoding,
// grouping, producer-side tanh all R5-proven. Per-phase pk_fma packs the two
// COLUMNS (same row) with the row-scalar broadcast via op_sel_hi:[0,...].

#define BB 128
#define TT 512
#define II 4
#define HH 512
#define OO 3
#define NREG_ 256

#define NTHREADS 512
#define MEMBERS 4
#define NGROUPS 64
#define NBLOCKS (NGROUPS * MEMBERS)

// d_ws layout (bytes): adat u64[2 coh][2 slot][64 g][512 col] = 1 MB
#define WS_PART  (2 * 2 * NGROUPS * HH * 8)

typedef unsigned long long u64;
typedef unsigned int u32;
typedef __attribute__((ext_vector_type(2))) float f32x2;

__device__ __forceinline__ u64 aload(const u64* p) {
    return __hip_atomic_load(p, __ATOMIC_RELAXED, __HIP_MEMORY_SCOPE_AGENT);
}
__device__ __forceinline__ void astore(u64* p, u64 v) {
    __hip_atomic_store(p, v, __ATOMIC_RELAXED, __HIP_MEMORY_SCOPE_AGENT);
}
__device__ __forceinline__ float fast_tanh(float x) {
    float ax = fabsf(x);
    float e  = __expf(2.0f * ax);
    float r  = 1.0f - 2.0f * __builtin_amdgcn_rcpf(e + 1.0f);
    return copysignf(r, x);
}

#define R16(M) M(0) M(1) M(2) M(3) M(4) M(5) M(6) M(7) \
               M(8) M(9) M(10) M(11) M(12) M(13) M(14) M(15)

// Weight pairs: w.x = W[k][memb*128+lane], w.y = W[k][memb*128+64+lane]
#define WLD(Q) \
    f32x2 w##Q##a, w##Q##b, w##Q##c, w##Q##d; \
    w##Q##a.x = Wp[(size_t)(4*Q+0)*HH]; w##Q##a.y = Wp[(size_t)(4*Q+0)*HH+64]; \
    w##Q##b.x = Wp[(size_t)(4*Q+1)*HH]; w##Q##b.y = Wp[(size_t)(4*Q+1)*HH+64]; \
    w##Q##c.x = Wp[(size_t)(4*Q+2)*HH]; w##Q##c.y = Wp[(size_t)(4*Q+2)*HH+64]; \
    w##Q##d.x = Wp[(size_t)(4*Q+3)*HH]; w##Q##d.y = Wp[(size_t)(4*Q+3)*HH+64];

// acc = (colA, colB) for ONE row: s broadcast to both halves via
// op_sel_hi[0]=0 (hi result also uses src0.lo). Verified modifier semantics
// in R5 (op_sel_hi[i]=0 => hi result reads operand i's LO half).
#define KSTEP(K, W) { \
    u32 s_ = __builtin_amdgcn_readlane(__float_as_uint(ar), (K)); \
    u64 ss = (u64)s_; \
    asm("v_pk_fma_f32 %0, %1, %2, %0 op_sel_hi:[0,1,1]" \
        : "+v"(acc) : "s"(ss), "v"(W)); }

#define MV(Q) KSTEP(4*Q+0, w##Q##a) KSTEP(4*Q+1, w##Q##b) \
              KSTEP(4*Q+2, w##Q##c) KSTEP(4*Q+3, w##Q##d)

// adat index: ((coh*2 + slot)*NGROUPS + g)*HH + col ; word = (tanh(h) | tag)
__global__ __launch_bounds__(NTHREADS) __attribute__((amdgpu_waves_per_eu(2, 2)))
void rnn_main(const float* __restrict__ x,
              const float* __restrict__ h0,
              const float* __restrict__ W_rec,
              const float* __restrict__ W_in,
              const float* __restrict__ bias_rec,
              const float* __restrict__ bias_in,
              float* __restrict__ hidden,      // (T+1, B, H) region of d_out
              u64* __restrict__ adat,          // exchange buffer in d_ws
              float* __restrict__ partials)
{
    const int tid  = threadIdx.x;
    const int bid  = blockIdx.x;
    const int xcd  = bid & 7;
    const int onx  = bid >> 3;
    const int memb = onx & (MEMBERS - 1);
    const int g    = xcd * 8 + (onx >> 2);    // 0..63
    const int rA   = g;                       // cohort A row
    const int rB   = 64 + g;                  // cohort B row
    const int wid  = tid >> 6;                // k-window [64*wid, 64*wid+64)
    const int lane = tid & 63;

    __shared__ float sc_s[2][128][9];         // per-cohort split-k partials
    __shared__ float xbuf[2][TT * II];        // x rows (A, B)
    __shared__ float win_s[II][128];
    __shared__ float ub_s[128];
    __shared__ float red_s[NTHREADS / 64];

    // ---- one-time staging ----
    for (int idx = tid; idx < TT * II; idx += NTHREADS) {
        xbuf[0][idx] = x[(size_t)rA * (TT * II) + idx];
        xbuf[1][idx] = x[(size_t)rB * (TT * II) + idx];
    }
    if (tid < II * 128) {
        int i = tid >> 7, jj = tid & 127;
        win_s[i][jj] = W_in[i * HH + memb * 128 + jj];
    }
    if (tid < 128) {
        ub_s[tid] = bias_rec[memb * 128 + tid] + bias_in[memb * 128 + tid];
    }

    // ---- W_rec slice into registers as float2 (colA,colB) pairs ----
    const float* Wp = W_rec + (size_t)(wid * 64) * HH + memb * 128 + lane;
    R16(WLD)

    // ---- prologue: publish tanh(h0) tag 1 for both cohorts ----
    const int fj  = tid & 127;                // finalize col (tid < 128)
    const int fjg = memb * 128 + fj;
    float hprevA = 0.0f, zprevA = 0.0f;
    float hprevB = 0.0f, zprevB = 0.0f;
    float racc = 0.0f;
    if (tid < 128) {
        hprevA = h0[(size_t)rA * HH + fjg];
        hprevB = h0[(size_t)rB * HH + fjg];
        u64 pA = (u64)__float_as_uint(fast_tanh(hprevA)) | ((u64)1u << 32);
        u64 pB = (u64)__float_as_uint(fast_tanh(hprevB)) | ((u64)1u << 32);
        astore(&adat[((size_t)(0 * 2 + 0) * NGROUPS + g) * HH + fjg], pA);
        astore(&adat[((size_t)(1 * 2 + 0) * NGROUPS + g) * HH + fjg], pB);
        hidden[(size_t)rA * HH + fjg] = hprevA;
        hidden[(size_t)rB * HH + fjg] = hprevB;
    }

#pragma unroll 1
    for (int t = 0; t < TT; ++t) {
        const int slot  = t & 1;
        const int slot2 = (t + 1) & 1;
        const u32 tagc  = (u32)(t + 1);
        const u64 tagp  = ((u64)(t + 2) << 32);

        // ================= PHASE A =================
        {
            const u64* pp = adat + ((size_t)(0 * 2 + slot) * NGROUPS + g) * HH
                            + wid * 64 + lane;
            u64 u;
            for (;;) {
                u = aload(pp);
                if (__all((u32)(u >> 32) == tagc)) break;
            }
            float ar = __uint_as_float((u32)u);

            f32x2 acc = {0.0f, 0.0f};
            R16(MV)
            sc_s[0][lane][wid]      = acc.x;
            sc_s[0][lane + 64][wid] = acc.y;
        }
        __syncthreads();
        if (tid < 128) {
            float q0 = sc_s[0][fj][0], q1 = sc_s[0][fj][1];
            float q2 = sc_s[0][fj][2], q3 = sc_s[0][fj][3];
            float q4 = sc_s[0][fj][4], q5 = sc_s[0][fj][5];
            float q6 = sc_s[0][fj][6], q7 = sc_s[0][fj][7];
            float z = ((q0 + q1) + (q2 + q3)) + ((q4 + q5) + (q6 + q7));
            z += ub_s[fj];
            const float* xr = &xbuf[0][t * II];
            z = fmaf(xr[0], win_s[0][fj], z);
            z = fmaf(xr[1], win_s[1][fj], z);
            z = fmaf(xr[2], win_s[2][fj], z);
            z = fmaf(xr[3], win_s[3][fj], z);
            float hn = 0.5f * hprevA + 0.5f * z;
            u64 pv = (u64)__float_as_uint(fast_tanh(hn)) | tagp;
            astore(&adat[((size_t)(0 * 2 + slot2) * NGROUPS + g) * HH + fjg], pv);
            hidden[(size_t)(t + 1) * BB * HH + (size_t)rA * HH + fjg] = hn;
            if (fjg < NREG_) {
                float d1 = hn - hprevA;
                racc = fmaf(d1, d1, racc);
                if (t > 0) { float d2 = z - zprevA; racc = fmaf(d2, d2, racc); }
                zprevA = z;
            }
            hprevA = hn;
        }

        // ================= PHASE B =================
        {
            const u64* pp = adat + ((size_t)(1 * 2 + slot) * NGROUPS + g) * HH
                            + wid * 64 + lane;
            u64 u;
            for (;;) {
                u = aload(pp);
                if (__all((u32)(u >> 32) == tagc)) break;
            }
            float ar = __uint_as_float((u32)u);

            f32x2 acc = {0.0f, 0.0f};
            R16(MV)
            sc_s[1][lane][wid]      = acc.x;
            sc_s[1][lane + 64][wid] = acc.y;
        }
        __syncthreads();
        if (tid < 128) {
            float q0 = sc_s[1][fj][0], q1 = sc_s[1][fj][1];
            float q2 = sc_s[1][fj][2], q3 = sc_s[1][fj][3];
            float q4 = sc_s[1][fj][4], q5 = sc_s[1][fj][5];
            float q6 = sc_s[1][fj][6], q7 = sc_s[1][fj][7];
            float z = ((q0 + q1) + (q2 + q3)) + ((q4 + q5) + (q6 + q7));
            z += ub_s[fj];
            const float* xr = &xbuf[1][t * II];
            z = fmaf(xr[0], win_s[0][fj], z);
            z = fmaf(xr[1], win_s[1][fj], z);
            z = fmaf(xr[2], win_s[2][fj], z);
            z = fmaf(xr[3], win_s[3][fj], z);
            float hn = 0.5f * hprevB + 0.5f * z;
            u64 pv = (u64)__float_as_uint(fast_tanh(hn)) | tagp;
            astore(&adat[((size_t)(1 * 2 + slot2) * NGROUPS + g) * HH + fjg], pv);
            hidden[(size_t)(t + 1) * BB * HH + (size_t)rB * HH + fjg] = hn;
            if (fjg < NREG_) {
                float d1 = hn - hprevB;
                racc = fmaf(d1, d1, racc);
                if (t > 0) { float d2 = z - zprevB; racc = fmaf(d2, d2, racc); }
                zprevB = z;
            }
            hprevB = hn;
        }
    }

    // ---- block-reduce reg partial (stored by ROLE for determinism) ----
    for (int off = 32; off; off >>= 1) racc += __shfl_down(racc, off);
    if ((tid & 63) == 0) red_s[tid >> 6] = racc;
    __syncthreads();
    if (tid == 0) {
        float s = 0.0f;
        for (int i = 0; i < NTHREADS / 64; ++i) s += red_s[i];
        partials[g * MEMBERS + memb] = s;
    }
}

// outputs[b][t][:] = hidden[t+1][b][:] @ W_out   (one wave per (b,t))
__global__ __launch_bounds__(256)
void rnn_out(const float* __restrict__ hidden,
             const float* __restrict__ W_out,
             float* __restrict__ outputs)
{
    __shared__ float wout_s[HH * OO];
    const int tid = threadIdx.x;
    for (int i = tid; i < HH * OO; i += 256) wout_s[i] = W_out[i];
    __syncthreads();

    const int gid  = blockIdx.x * 4 + (tid >> 6);
    const int lane = tid & 63;
    const int b = gid >> 9;
    const int t = gid & (TT - 1);
    const float* hp = hidden + (size_t)(t + 1) * BB * HH + (size_t)b * HH;

    float o0 = 0.0f, o1 = 0.0f, o2 = 0.0f;
#pragma unroll
    for (int q = 0; q < 8; ++q) {
        int k = lane + 64 * q;
        float hv = hp[k];
        o0 = fmaf(hv, wout_s[k * 3 + 0], o0);
        o1 = fmaf(hv, wout_s[k * 3 + 1], o1);
        o2 = fmaf(hv, wout_s[k * 3 + 2], o2);
    }
    for (int off = 32; off; off >>= 1) {
        o0 += __shfl_down(o0, off);
        o1 += __shfl_down(o1, off);
        o2 += __shfl_down(o2, off);
    }
    if (lane == 0) {
        float* op = outputs + (size_t)(b * TT + t) * OO;
        op[0] = o0; op[1] = o1; op[2] = o2;
    }
}

__global__ __launch_bounds__(256)
void rnn_tcr(const float* __restrict__ partials, float* __restrict__ tcr)
{
    __shared__ float red[4];
    const int tid = threadIdx.x;
    float v = partials[tid];
    for (int off = 32; off; off >>= 1) v += __shfl_down(v, off);
    if ((tid & 63) == 0) red[tid >> 6] = v;
    __syncthreads();
    if (tid == 0) {
        float s = red[0] + red[1] + red[2] + red[3];
        *tcr = s * (1.0f / ((float)TT * (float)BB * (float)NREG_));
    }
}

extern "C" void kernel_launch(void* const* d_in, const int* in_sizes, int n_in,
                              void* d_out, int out_size, void* d_ws, size_t ws_size,
                              hipStream_t stream)
{
    (void)in_sizes; (void)n_in; (void)out_size; (void)ws_size;

    const float* x     = (const float*)d_in[0];
    const float* h0    = (const float*)d_in[1];
    const float* W_rec = (const float*)d_in[2];
    const float* W_in  = (const float*)d_in[3];
    const float* W_out = (const float*)d_in[4];
    const float* brec  = (const float*)d_in[5];
    const float* bin   = (const float*)d_in[6];

    float* out     = (float*)d_out;
    float* outputs = out;
    float* hidden  = out + (size_t)BB * TT * OO;
    float* tcr     = out + (size_t)BB * TT * OO + (size_t)(TT + 1) * BB * HH;

    u64*   adat     = (u64*)d_ws;
    float* partials = (float*)((char*)d_ws + WS_PART);

    // zero exchange-buffer tags every call (graph replays reuse d_ws)
    (void)hipMemsetAsync(d_ws, 0, WS_PART, stream);

    void* args[] = { (void*)&x, (void*)&h0, (void*)&W_rec, (void*)&W_in,
                     (void*)&brec, (void*)&bin, (void*)&hidden,
                     (void*)&adat, (void*)&partials };
    (void)hipLaunchCooperativeKernel((const void*)rnn_main,
                                     dim3(NBLOCKS), dim3(NTHREADS),
                                     args, 0, stream);

    rnn_out<<<dim3((BB * TT) / 4), dim3(256), 0, stream>>>(hidden, W_out, outputs);
    rnn_tcr<<<dim3(1), dim3(256), 0, stream>>>(partials, tcr);
}